// Round 1
// baseline (48.906 us; speedup 1.0000x reference)
//
#include <hip/hip_runtime.h>
#include <math.h>

#define PI_F 3.14159265358979323846f
#define F0_C 0.91f
#define NL   512      // EH*EW = 16*32
#define EH_C 16
#define EW_C 32
#define P_PTS  8192
#define PT_PTS 65536

__device__ __forceinline__ float safe_div_f(float num, float den) {
    return (fabsf(den) > 1e-12f) ? (num / den) : 0.0f;
}

// out = grd_rgb * acc  (full init of d_out; scatter kernel overwrites selected rows)
__global__ __launch_bounds__(256) void bg_kernel(const float* __restrict__ grd_rgb,
                                                 const float* __restrict__ grd_acc,
                                                 float* __restrict__ out) {
    int i = blockIdx.x * 256 + threadIdx.x;
    if (i < PT_PTS) {
        float a = grd_acc[i];
        out[3*i+0] = grd_rgb[3*i+0] * a;
        out[3*i+1] = grd_rgb[3*i+1] * a;
        out[3*i+2] = grd_rgb[3*i+2] * a;
    }
}

// one wave64 per point; lanes split the 512 lights
__global__ __launch_bounds__(256) void render_kernel(
    const float* __restrict__ surf,      // P,3
    const float* __restrict__ ray_o,     // P,3
    const float* __restrict__ norm_raw,  // P,3
    const float* __restrict__ albedo,    // P,3
    const float* __restrict__ rough,     // P,1
    const float* __restrict__ lvis,      // P,512
    const float* __restrict__ xyz,       // 512,3
    const float* __restrict__ area,      // 512
    const float* __restrict__ probe,     // 512,3
    const float* __restrict__ grd_rgb,   // Pt,3
    const float* __restrict__ grd_acc,   // Pt
    const int*   __restrict__ inds,      // P (sorted)
    float* __restrict__ out)             // Pt,3
{
    __shared__ float s_xyz[NL*3];
    __shared__ float s_ldir[NL*3];
    __shared__ float s_probe[NL*3];
    __shared__ float s_area[NL];

    for (int i = threadIdx.x; i < NL; i += 256) {
        float x = xyz[3*i+0], y = xyz[3*i+1], z = xyz[3*i+2];
        s_xyz[3*i+0] = x; s_xyz[3*i+1] = y; s_xyz[3*i+2] = z;
        float inv = 1.0f / (sqrtf(x*x + y*y + z*z) + 1e-8f);
        s_ldir[3*i+0] = x*inv; s_ldir[3*i+1] = y*inv; s_ldir[3*i+2] = z*inv;
        s_probe[3*i+0] = probe[3*i+0];
        s_probe[3*i+1] = probe[3*i+1];
        s_probe[3*i+2] = probe[3*i+2];
        s_area[i] = area[i];
    }
    __syncthreads();

    const int wave = threadIdx.x >> 6;
    const int lane = threadIdx.x & 63;
    const int p    = blockIdx.x * 4 + wave;   // grid = P/4 exactly

    // per-point precompute (redundant per lane, cheap)
    float sx = surf[3*p+0], sy = surf[3*p+1], sz = surf[3*p+2];
    float nx = norm_raw[3*p+0], ny = norm_raw[3*p+1], nz = norm_raw[3*p+2];
    {
        float inv = 1.0f / (sqrtf(nx*nx + ny*ny + nz*nz) + 1e-8f);
        nx *= inv; ny *= inv; nz *= inv;
    }
    float cx = ray_o[3*p+0] - sx, cy = ray_o[3*p+1] - sy, cz = ray_o[3*p+2] - sz;
    {
        float inv = 1.0f / (sqrtf(cx*cx + cy*cy + cz*cz) + 1e-8f);
        cx *= inv; cy *= inv; cz *= inv;
    }
    float cos_v  = nx*cx + ny*cy + nz*cz;
    float r      = rough[p];
    float alpha  = r*r;               // "alpha" in ref
    float alpha2 = alpha*alpha;       // alpha**2 in ref
    float cvsq   = fminf(fmaxf(cos_v*cos_v, 0.0f), 1.0f);
    float tvsq   = fminf(fmaxf(safe_div_f(1.0f - cvsq, cvsq), 0.0f), 1e10f);
    float gden   = 1.0f + sqrtf(1.0f + alpha2 * tvsq);   // >= 2, never ~0
    float ab0 = albedo[3*p+0] * (1.0f/PI_F);
    float ab1 = albedo[3*p+1] * (1.0f/PI_F);
    float ab2 = albedo[3*p+2] * (1.0f/PI_F);
    float acv = fabsf(cos_v);

    float acc0 = 0.0f, acc1 = 0.0f, acc2 = 0.0f;

    for (int l = lane; l < NL; l += 64) {
        // surf2light
        float dx = s_xyz[3*l+0] - sx, dy = s_xyz[3*l+1] - sy, dz = s_xyz[3*l+2] - sz;
        float inv = 1.0f / (sqrtf(dx*dx + dy*dy + dz*dz) + 1e-8f);
        float slx = dx*inv, sly = dy*inv, slz = dz*inv;

        // ldot with precomputed normalized light dir
        float ldot = s_ldir[3*l+0]*nx + s_ldir[3*l+1]*ny + s_ldir[3*l+2]*nz;

        // envmap bilinear sample at direction s2l
        float zc    = fminf(fmaxf(slz, -1.0f + 1e-6f), 1.0f - 1e-6f);
        float theta = acosf(zc);
        float phi   = atan2f(sly, slx);
        float v  = theta * (EH_C / PI_F) - 0.5f;
        float u  = (phi * (1.0f/(2.0f*PI_F)) + 0.5f) * EW_C - 0.5f;
        float v0f = floorf(v), u0f = floorf(u);
        float fv = v - v0f,  fu = u - u0f;
        int v0i = min(max((int)v0f, 0), EH_C-1);
        int v1i = min(v0i + 1, EH_C-1);
        int u0i = ((int)u0f) & (EW_C-1);
        int u1i = (u0i + 1) & (EW_C-1);
        const float* p00 = &s_probe[3*(v0i*EW_C + u0i)];
        const float* p01 = &s_probe[3*(v0i*EW_C + u1i)];
        const float* p10 = &s_probe[3*(v1i*EW_C + u0i)];
        const float* p11 = &s_probe[3*(v1i*EW_C + u1i)];
        float w00 = (1.0f-fu)*(1.0f-fv), w01 = fu*(1.0f-fv);
        float w10 = (1.0f-fu)*fv,        w11 = fu*fv;
        float li0 = p00[0]*w00 + p01[0]*w01 + p10[0]*w10 + p11[0]*w11;
        float li1 = p00[1]*w00 + p01[1]*w01 + p10[1]*w10 + p11[1]*w11;
        float li2 = p00[2]*w00 + p01[2]*w01 + p10[2]*w10 + p11[2]*w11;

        // shade scalar part (lvis * ldot * area); light color applied per channel
        float sh = lvis[p*NL + l] * ldot * s_area[l];

        // microfacet brdf
        float hx = slx + cx, hy = sly + cy, hz = slz + cz;
        float invh = 1.0f / (sqrtf(hx*hx + hy*hy + hz*hz) + 1e-8f);
        hx *= invh; hy *= invh; hz *= invh;

        float ldh = slx*hx + sly*hy + slz*hz;
        float om  = 1.0f - ldh;
        float om2 = om*om;
        float f   = F0_C + (1.0f - F0_C) * om2*om2*om;

        float cos_m = hx*nx + hy*ny + hz*nz;
        float cm2   = cos_m*cos_m;
        float tmsq  = safe_div_f(1.0f - cm2, cm2);
        float chi_m = (cos_m > 0.0f) ? 1.0f : 0.0f;
        float dd    = alpha2 + tmsq;
        float dden  = PI_F * cm2*cm2 * dd*dd;
        float dter  = safe_div_f(alpha2 * chi_m, dden);

        float cos_hv = hx*cx + hy*cy + hz*cz;
        float chi_g  = (safe_div_f(cos_hv, cos_v) > 0.0f) ? 1.0f : 0.0f;
        float g      = chi_g * 2.0f / gden;

        float ldn   = slx*nx + sly*ny + slz*nz;
        float micro = safe_div_f(f*g*dter, 4.0f * fabsf(ldn) * acv);

        acc0 += (micro + ab0) * sh * li0;
        acc1 += (micro + ab1) * sh * li1;
        acc2 += (micro + ab2) * sh * li2;
    }

    // wave64 tree reduce
    for (int off = 32; off > 0; off >>= 1) {
        acc0 += __shfl_xor(acc0, off);
        acc1 += __shfl_xor(acc1, off);
        acc2 += __shfl_xor(acc2, off);
    }

    if (lane == 0) {
        int idx = inds[p];
        // numpy scatter-set: last write wins; inds sorted -> only last occurrence writes
        bool last = (p == P_PTS-1) || (inds[p+1] != idx);
        if (last) {
            float a  = grd_acc[idx];
            float rgb[3] = {acc0, acc1, acc2};
            #pragma unroll
            for (int c = 0; c < 3; ++c) {
                float x = fminf(fmaxf(rgb[c], 0.0f), 1.0f);
                float s = (x <= 0.0031308f)
                        ? 12.92f * x
                        : 1.055f * powf(fmaxf(x, 1e-8f), 1.0f/2.4f) - 0.055f;
                out[3*idx+c] = grd_rgb[3*idx+c] * a + s * (1.0f - a);
            }
        }
    }
}

extern "C" void kernel_launch(void* const* d_in, const int* in_sizes, int n_in,
                              void* d_out, int out_size, void* d_ws, size_t ws_size,
                              hipStream_t stream) {
    const float* surf      = (const float*)d_in[0];
    const float* ray_o     = (const float*)d_in[1];
    const float* norm_raw  = (const float*)d_in[2];
    const float* albedo    = (const float*)d_in[3];
    const float* roughness = (const float*)d_in[4];
    const float* lvis      = (const float*)d_in[5];
    const float* xyz       = (const float*)d_in[6];
    const float* area      = (const float*)d_in[7];
    const float* probe     = (const float*)d_in[8];
    const float* grd_rgb   = (const float*)d_in[9];
    const float* grd_acc   = (const float*)d_in[10];
    const int*   inds      = (const int*)d_in[11];
    float* out = (float*)d_out;

    bg_kernel<<<PT_PTS/256, 256, 0, stream>>>(grd_rgb, grd_acc, out);
    render_kernel<<<P_PTS/4, 256, 0, stream>>>(surf, ray_o, norm_raw, albedo,
        roughness, lvis, xyz, area, probe, grd_rgb, grd_acc, inds, out);
}

// Round 3
// 32.560 us; speedup vs baseline: 1.5020x; 1.5020x over previous
//
#include <hip/hip_runtime.h>
#include <math.h>

#define NL     512      // EH*EW = 16*32
#define EH_C   16
#define EW_C   32
#define P_PTS  8192
#define PT_PTS 65536

__device__ __forceinline__ float rcp_f(float x)  { return __builtin_amdgcn_rcpf(x); }
__device__ __forceinline__ float rsq_f(float x)  { return __builtin_amdgcn_rsqf(x); }
__device__ __forceinline__ float sqrt_f(float x) { return __builtin_amdgcn_sqrtf(x); }

// atan(a) for a in [0,1]; cephes single-precision minimax + tan(pi/8) reduction,
// max abs err ~1e-7 rad.
__device__ __forceinline__ float atan01(float a) {
    bool  big = a > 0.41421356f;
    float t   = big ? (a - 1.0f) * rcp_f(a + 1.0f) : a;
    float s   = t * t;
    float p   = fmaf(fmaf(fmaf(8.05374449538e-2f, s, -1.38776856032e-1f), s,
                          1.99777106478e-1f), s, -3.33329491539e-1f);
    float r   = fmaf(p * s, t, t);
    return big ? r + 0.7853981634f : r;
}

__device__ __forceinline__ float fast_atan2(float y, float x) {
    float ax = fabsf(x), ay = fabsf(y);
    float mx = fmaxf(ax, ay), mn = fminf(ax, ay);
    float a  = mn * rcp_f(fmaxf(mx, 1e-37f));   // guard 0/0 -> 0
    float r  = atan01(a);
    if (ay > ax)  r = 1.5707963268f - r;
    if (x < 0.0f) r = 3.1415926536f - r;
    return copysignf(r, y);
}

// acos(z) = atan2(sqrt(1-z^2), z) specialized for y >= 0; z pre-clamped to
// +-0.999999 so sqrt arg >= ~2e-6 and max(az,sq) >= 1/sqrt(2): no guards needed.
__device__ __forceinline__ float fast_acos(float z) {
    float s2 = fmaf(-z, z, 1.0f);
    float sq = sqrt_f(s2);
    float az = fabsf(z);
    float mx = fmaxf(az, sq), mn = fminf(az, sq);
    float r  = atan01(mn * rcp_f(mx));
    if (sq > az)  r = 1.5707963268f - r;
    if (z < 0.0f) r = 3.1415926536f - r;
    return r;
}

// out = grd_rgb * acc  (full init of d_out; render overwrites scattered rows)
__global__ __launch_bounds__(256) void bg_kernel(const float* __restrict__ grd_rgb,
                                                 const float* __restrict__ grd_acc,
                                                 float* __restrict__ out) {
    int i = blockIdx.x * 256 + threadIdx.x;
    if (i < PT_PTS) {
        float a = grd_acc[i];
        out[3*i+0] = grd_rgb[3*i+0] * a;
        out[3*i+1] = grd_rgb[3*i+1] * a;
        out[3*i+2] = grd_rgb[3*i+2] * a;
    }
}

// one wave64 per point; lanes split the 512 lights
__global__ __launch_bounds__(256) void render_kernel(
    const float* __restrict__ surf,      // P,3
    const float* __restrict__ ray_o,     // P,3
    const float* __restrict__ norm_raw,  // P,3
    const float* __restrict__ albedo,    // P,3
    const float* __restrict__ rough,     // P,1
    const float* __restrict__ lvis,      // P,512
    const float* __restrict__ xyz,       // 512,3
    const float* __restrict__ area,      // 512
    const float* __restrict__ probe,     // 512,3
    const float* __restrict__ grd_rgb,   // Pt,3
    const float* __restrict__ grd_acc,   // Pt
    const int*   __restrict__ inds,      // P (sorted)
    float* __restrict__ out)             // Pt,3
{
    __shared__ float4 sA[NL];   // xyz.xyz, w = area/(|xyz|+1e-8)
    __shared__ float4 sP[NL];   // probe rgb, pad

    for (int i = threadIdx.x; i < NL; i += 256) {
        float x = xyz[3*i+0], y = xyz[3*i+1], z = xyz[3*i+2];
        float aw = area[i] / (sqrtf(x*x + y*y + z*z) + 1e-8f);
        sA[i] = make_float4(x, y, z, aw);
        sP[i] = make_float4(probe[3*i+0], probe[3*i+1], probe[3*i+2], 0.0f);
    }
    __syncthreads();

    const int lane = threadIdx.x & 63;
    const int p    = blockIdx.x * 4 + (threadIdx.x >> 6);

    // ---- per-point precompute (redundant per lane, amortized over 8 lights) ----
    float sx = surf[3*p+0], sy = surf[3*p+1], sz = surf[3*p+2];
    float nx = norm_raw[3*p+0], ny = norm_raw[3*p+1], nz = norm_raw[3*p+2];
    { float inv = 1.0f / (sqrtf(nx*nx + ny*ny + nz*nz) + 1e-8f); nx*=inv; ny*=inv; nz*=inv; }
    float cx = ray_o[3*p+0]-sx, cy = ray_o[3*p+1]-sy, cz = ray_o[3*p+2]-sz;
    { float inv = 1.0f / (sqrtf(cx*cx + cy*cy + cz*cz) + 1e-8f); cx*=inv; cy*=inv; cz*=inv; }

    float cos_v  = nx*cx + ny*cy + nz*cz;
    float r      = rough[p];
    float alpha2 = (r*r)*(r*r);
    float cvsq   = fminf(fmaxf(cos_v*cos_v, 0.0f), 1.0f);
    float tvsq   = (cvsq > 1e-12f) ? fminf((1.0f - cvsq)/cvsq, 1e10f) : 0.0f;
    float gden   = 1.0f + sqrtf(1.0f + alpha2 * tvsq);
    float g2inv  = (fabsf(cos_v) > 1e-12f) ? 2.0f / gden : 0.0f;  // chi_g cos_v gate folded in
    float a2pi   = alpha2 * 0.3183098862f;    // alpha^2 / pi
    float a2m1   = alpha2 - 1.0f;
    float acv4   = 4.0f * fabsf(cos_v);
    float ab0 = albedo[3*p+0] * 0.3183098862f;
    float ab1 = albedo[3*p+1] * 0.3183098862f;
    float ab2 = albedo[3*p+2] * 0.3183098862f;
    const float* lv = lvis + p*NL;

    float acc0 = 0.0f, acc1 = 0.0f, acc2 = 0.0f;

    #pragma unroll 2
    for (int it = 0; it < 8; ++it) {
        int l = lane + it*64;
        float  lvv = lv[l];
        float4 A   = sA[l];

        // surf2light (|d| ~ O(10): no zero guard needed)
        float dx = A.x - sx, dy = A.y - sy, dz = A.z - sz;
        float inv = rsq_f(fmaf(dx,dx, fmaf(dy,dy, dz*dz)));
        float slx = dx*inv, sly = dy*inv, slz = dz*inv;

        // ldot*area*invlen folded: sh = lvis * (n . xyz) * (area/|xyz|)
        float ldraw = fmaf(A.x,nx, fmaf(A.y,ny, A.z*nz));
        float sh = lvv * ldraw * A.w;

        // ---- envmap bilinear ----
        float zc = fminf(fmaxf(slz, -0.999999f), 0.999999f);
        float v  = fmaf(fast_acos(zc),        5.0929581790f, -0.5f);  // theta*16/pi - 0.5
        float u  = fmaf(fast_atan2(sly, slx), 5.0929581790f, 15.5f);  // phi*16/pi + 15.5
        float v0f = floorf(v), u0f = floorf(u);
        float fv = v - v0f, fu = u - u0f;
        int v0i = (int)v0f; v0i = v0i < 0 ? 0 : (v0i > EH_C-1 ? EH_C-1 : v0i);
        int v1i = v0i + 1 > EH_C-1 ? EH_C-1 : v0i + 1;
        int u0i = ((int)u0f) & (EW_C-1);
        int u1i = (u0i + 1) & (EW_C-1);
        int r0 = v0i << 5, r1 = v1i << 5;
        float4 t00 = sP[r0 + u0i], t01 = sP[r0 + u1i];
        float4 t10 = sP[r1 + u0i], t11 = sP[r1 + u1i];
        float w11 = fu*fv, w10 = fv - w11, w01 = fu - w11, w00 = 1.0f - fu - fv + w11;
        float li0 = fmaf(t00.x,w00, fmaf(t01.x,w01, fmaf(t10.x,w10, t11.x*w11)));
        float li1 = fmaf(t00.y,w00, fmaf(t01.y,w01, fmaf(t10.y,w10, t11.y*w11)));
        float li2 = fmaf(t00.z,w00, fmaf(t01.z,w01, fmaf(t10.z,w10, t11.z*w11)));

        // ---- microfacet ----
        float hx = slx+cx, hy = sly+cy, hz = slz+cz;
        float ih = rsq_f(fmaxf(fmaf(hx,hx, fmaf(hy,hy, hz*hz)), 1e-24f));
        hx *= ih; hy *= ih; hz *= ih;

        float ldh = fmaf(slx,hx, fmaf(sly,hy, slz*hz));
        float om  = 1.0f - ldh, om2 = om*om;
        float f   = fmaf(om2*om2*om, 0.09f, 0.91f);

        // D: pi*cm^4*(a2+tan^2m)^2 == pi*(1+cm2*(a2-1))^2 ; ref's safe_div edge
        // (dden<=1e-12) collapses to cos_m <= 1e-6 given alpha >= 0.01
        float cm = fmaf(hx,nx, fmaf(hy,ny, hz*nz));
        float q  = fmaf(cm*cm, a2m1, 1.0f);
        float dterm = (cm > 1e-6f) ? a2pi * rcp_f(q*q) : 0.0f;

        // G: chi_g = sign(cos_hv/cos_v) > 0  (cos_v gate pre-folded into g2inv)
        float chv = fmaf(hx,cx, fmaf(hy,cy, hz*cz));
        float gg  = (chv * cos_v > 0.0f) ? g2inv : 0.0f;

        float ldn = fmaf(slx,nx, fmaf(sly,ny, slz*nz));
        float den = fabsf(ldn) * acv4;
        float num = f * gg * dterm;
        float micro = (den > 1e-12f) ? num * rcp_f(den) : 0.0f;

        acc0 = fmaf(micro + ab0, sh*li0, acc0);
        acc1 = fmaf(micro + ab1, sh*li1, acc1);
        acc2 = fmaf(micro + ab2, sh*li2, acc2);
    }

    // wave64 butterfly reduce
    for (int off = 32; off > 0; off >>= 1) {
        acc0 += __shfl_xor(acc0, off);
        acc1 += __shfl_xor(acc1, off);
        acc2 += __shfl_xor(acc2, off);
    }

    if (lane == 0) {
        int idx = inds[p];
        // numpy scatter-set: last write wins; inds sorted -> only last occurrence writes
        bool last = (p == P_PTS-1) || (inds[p+1] != idx);
        if (last) {
            float a = grd_acc[idx];
            float rgb[3] = {acc0, acc1, acc2};
            #pragma unroll
            for (int c = 0; c < 3; ++c) {
                float x = fminf(fmaxf(rgb[c], 0.0f), 1.0f);
                float s = (x <= 0.0031308f)
                        ? 12.92f * x
                        : fmaf(1.055f, exp2f(log2f(x) * (1.0f/2.4f)), -0.055f);
                out[3*idx+c] = fmaf(grd_rgb[3*idx+c], a, s * (1.0f - a));
            }
        }
    }
}

extern "C" void kernel_launch(void* const* d_in, const int* in_sizes, int n_in,
                              void* d_out, int out_size, void* d_ws, size_t ws_size,
                              hipStream_t stream) {
    const float* surf      = (const float*)d_in[0];
    const float* ray_o     = (const float*)d_in[1];
    const float* norm_raw  = (const float*)d_in[2];
    const float* albedo    = (const float*)d_in[3];
    const float* roughness = (const float*)d_in[4];
    const float* lvis      = (const float*)d_in[5];
    const float* xyz       = (const float*)d_in[6];
    const float* area      = (const float*)d_in[7];
    const float* probe     = (const float*)d_in[8];
    const float* grd_rgb   = (const float*)d_in[9];
    const float* grd_acc   = (const float*)d_in[10];
    const int*   inds      = (const int*)d_in[11];
    float* out = (float*)d_out;

    bg_kernel<<<PT_PTS/256, 256, 0, stream>>>(grd_rgb, grd_acc, out);
    render_kernel<<<P_PTS/4, 256, 0, stream>>>(surf, ray_o, norm_raw, albedo,
        roughness, lvis, xyz, area, probe, grd_rgb, grd_acc, inds, out);
}

// Round 5
// 27.712 us; speedup vs baseline: 1.7648x; 1.1749x over previous
//
#include <hip/hip_runtime.h>
#include <math.h>

#define NL     512      // EH*EW = 16*32
#define EH_C   16
#define EW_C   32
#define P_PTS  8192
#define PT_PTS 65536

__device__ __forceinline__ float rcp_f(float x)  { return __builtin_amdgcn_rcpf(x); }
__device__ __forceinline__ float rsq_f(float x)  { return __builtin_amdgcn_rsqf(x); }
__device__ __forceinline__ float sqrt_f(float x) { return __builtin_amdgcn_sqrtf(x); }

// out = grd_rgb * acc, fully vectorized: thread j handles 4 points (12 floats).
__global__ __launch_bounds__(256) void bg_kernel(const float4* __restrict__ rgbv,
                                                 const float4* __restrict__ accv,
                                                 float4* __restrict__ outv) {
    int j = blockIdx.x * 256 + threadIdx.x;   // 16384 threads
    float4 a  = accv[j];
    float4 r0 = rgbv[3*j+0], r1 = rgbv[3*j+1], r2 = rgbv[3*j+2];
    outv[3*j+0] = make_float4(r0.x*a.x, r0.y*a.x, r0.z*a.x, r0.w*a.y);
    outv[3*j+1] = make_float4(r1.x*a.y, r1.y*a.y, r1.z*a.z, r1.w*a.z);
    outv[3*j+2] = make_float4(r2.x*a.z, r2.y*a.w, r2.z*a.w, r2.w*a.w);
}

// one wave64 per point; lanes split the 512 lights
__global__ __launch_bounds__(256, 8) void render_kernel(
    const float* __restrict__ surf,      // P,3
    const float* __restrict__ ray_o,     // P,3
    const float* __restrict__ norm_raw,  // P,3
    const float* __restrict__ albedo,    // P,3
    const float* __restrict__ rough,     // P,1
    const float* __restrict__ lvis,      // P,512
    const float* __restrict__ xyz,       // 512,3
    const float* __restrict__ area,      // 512
    const float* __restrict__ probe,     // 512,3
    const float* __restrict__ grd_rgb,   // Pt,3
    const float* __restrict__ grd_acc,   // Pt
    const int*   __restrict__ inds,      // P (sorted)
    float* __restrict__ out)             // Pt,3
{
    __shared__ float4 sA[NL];   // xyz.xyz, w = area/(|xyz|+1e-8)
    __shared__ float4 sP[NL];   // probe rgb, pad

    for (int i = threadIdx.x; i < NL; i += 256) {
        float x = xyz[3*i+0], y = xyz[3*i+1], z = xyz[3*i+2];
        float aw = area[i] / (sqrtf(x*x + y*y + z*z) + 1e-8f);
        sA[i] = make_float4(x, y, z, aw);
        sP[i] = make_float4(probe[3*i+0], probe[3*i+1], probe[3*i+2], 0.0f);
    }
    __syncthreads();

    const int lane = threadIdx.x & 63;
    const int p    = blockIdx.x * 4 + (threadIdx.x >> 6);

    // ---- per-point precompute (redundant per lane, amortized over 8 lights) ----
    float sx = surf[3*p+0], sy = surf[3*p+1], sz = surf[3*p+2];
    float nx = norm_raw[3*p+0], ny = norm_raw[3*p+1], nz = norm_raw[3*p+2];
    { float inv = 1.0f / (sqrtf(nx*nx + ny*ny + nz*nz) + 1e-8f); nx*=inv; ny*=inv; nz*=inv; }
    float cx = ray_o[3*p+0]-sx, cy = ray_o[3*p+1]-sy, cz = ray_o[3*p+2]-sz;
    { float inv = 1.0f / (sqrtf(cx*cx + cy*cy + cz*cz) + 1e-8f); cx*=inv; cy*=inv; cz*=inv; }

    float cos_v  = nx*cx + ny*cy + nz*cz;
    float r      = rough[p];
    float alpha2 = (r*r)*(r*r);
    float cvsq   = fminf(fmaxf(cos_v*cos_v, 0.0f), 1.0f);
    float tvsq   = (cvsq > 1e-12f) ? fminf((1.0f - cvsq)/cvsq, 1e10f) : 0.0f;
    float gden   = 1.0f + sqrtf(1.0f + alpha2 * tvsq);
    float g2inv  = (fabsf(cos_v) > 1e-12f) ? 2.0f / gden : 0.0f;  // chi_g cos_v==0 edge folded
    float g2a    = g2inv * alpha2 * 0.3183098862f;                // g * alpha^2/pi, hoisted
    float a2m1   = alpha2 - 1.0f;
    float acv4   = 4.0f * fabsf(cos_v);
    float ab0 = albedo[3*p+0] * 0.3183098862f;
    float ab1 = albedo[3*p+1] * 0.3183098862f;
    float ab2 = albedo[3*p+2] * 0.3183098862f;
    const float* lv = lvis + p*NL;

    float acc0 = 0.0f, acc1 = 0.0f, acc2 = 0.0f;

    #pragma unroll 2
    for (int it = 0; it < 8; ++it) {
        int l = lane + it*64;
        float  lvv = lv[l];
        float4 A   = sA[l];

        // surf2light (|d| ~ O(10): no zero guard needed)
        float dx = A.x - sx, dy = A.y - sy, dz = A.z - sz;
        float inv = rsq_f(fmaf(dx,dx, fmaf(dy,dy, dz*dz)));
        float slx = dx*inv, sly = dy*inv, slz = dz*inv;

        // sh = lvis * (n . xyz) * (area/|xyz|)
        float ldraw = fmaf(A.x,nx, fmaf(A.y,ny, A.z*nz));
        float sh = lvv * ldraw * A.w;

        // ---- envmap coords, scaled by K=16/pi with offsets folded ----
        // v = acos(zc)*K - 0.5 ; acos via sqrt(1-x)*poly3(x) (A&S 4.4.45, K-scaled)
        float zc = fminf(fmaxf(slz, -0.999999f), 0.999999f);
        float xa = fabsf(zc);
        float pc = fmaf(fmaf(fmaf(-0.0953875f, xa, 0.378208f), xa, -1.0802913f), xa,
                        7.9996562f);
        float vpre = sqrt_f(1.0f - xa) * pc;                 // acos(|zc|)*K
        float v = (zc < 0.0f) ? (15.5f - vpre) : (vpre - 0.5f);

        // u = atan2(sly,slx)*K + 15.5 ; deg-9 odd minimax on [0,1], K-scaled.
        // Quadrant constants are exact in u-units: K*pi/2 = 8, K*pi = 16.
        float ax = fabsf(slx), ay = fabsf(sly);
        float mx = fmaxf(ax, ay), mn = fminf(ax, ay);
        float a  = mn * rcp_f(fmaxf(mx, 1e-37f));
        float s  = a * a;
        float pu = fmaf(fmaf(fmaf(fmaf(0.106112f, s, -0.433578f), s, 0.917450f), s,
                             -1.682201f), s, 5.0922757f);
        float rk = a * pu;                                   // atan(a)*K
        rk = (ay > ax)    ? 8.0f  - rk : rk;
        rk = (slx < 0.0f) ? 16.0f - rk : rk;
        float u = copysignf(rk, sly) + 15.5f;

        // ---- bilinear fetch ----
        float v0f = floorf(v), u0f = floorf(u);
        float fv = v - v0f, fu = u - u0f;
        int v0i = (int)v0f; v0i = min(max(v0i, 0), EH_C-1);
        int v1i = min(v0i + 1, EH_C-1);
        int u0i = ((int)u0f) & (EW_C-1);
        int u1i = (u0i + 1) & (EW_C-1);
        int r0 = v0i << 5, r1 = v1i << 5;
        float4 t00 = sP[r0 + u0i], t01 = sP[r0 + u1i];
        float4 t10 = sP[r1 + u0i], t11 = sP[r1 + u1i];
        float w11 = fu*fv, w10 = fv - w11, w01 = fu - w11;
        float w00 = (1.0f - fu) - w10;
        float li0 = fmaf(t00.x,w00, fmaf(t01.x,w01, fmaf(t10.x,w10, t11.x*w11)));
        float li1 = fmaf(t00.y,w00, fmaf(t01.y,w01, fmaf(t10.y,w10, t11.y*w11)));
        float li2 = fmaf(t00.z,w00, fmaf(t01.z,w01, fmaf(t10.z,w10, t11.z*w11)));

        // ---- microfacet via half-vector identities (s2l, c unit vectors):
        // |h|^2 = 2+2*hdot ; ldh = (1+hdot)/|h| ; cos_m = (ldn+cos_v)/|h| ; cos_hv == ldh
        float hdot = fmaf(slx,cx, fmaf(sly,cy, slz*cz));
        float h2   = fmaxf(fmaf(2.0f, hdot, 2.0f), 1e-12f);
        float ih   = rsq_f(h2);
        float ldh  = fmaf(hdot, ih, ih);
        float ldn  = fmaf(slx,nx, fmaf(sly,ny, slz*nz));
        float cm   = (ldn + cos_v) * ih;

        float om  = 1.0f - ldh, om2 = om*om;
        float f   = fmaf(om2*om2*om, 0.09f, 0.91f);

        float q  = fmaf(cm*cm, a2m1, 1.0f);        // == cm^4*(a2+tan^2m) collapsed
        float dr = rcp_f(q*q);
        float den  = fabsf(ldn) * acv4;
        float rden = rcp_f(den);

        float micro = f * g2a * (dr * rden);
        bool  gate  = (cm > 1e-6f) & (ldh * cos_v > 0.0f) & (den > 1e-12f);
        micro = gate ? micro : 0.0f;

        acc0 = fmaf(micro + ab0, sh*li0, acc0);
        acc1 = fmaf(micro + ab1, sh*li1, acc1);
        acc2 = fmaf(micro + ab2, sh*li2, acc2);
    }

    // wave64 butterfly reduce
    for (int off = 32; off > 0; off >>= 1) {
        acc0 += __shfl_xor(acc0, off);
        acc1 += __shfl_xor(acc1, off);
        acc2 += __shfl_xor(acc2, off);
    }

    if (lane == 0) {
        int idx = inds[p];
        // numpy scatter-set: last write wins; inds sorted -> only last occurrence writes
        bool last = (p == P_PTS-1) || (inds[p+1] != idx);
        if (last) {
            float a = grd_acc[idx];
            float rgb[3] = {acc0, acc1, acc2};
            #pragma unroll
            for (int c = 0; c < 3; ++c) {
                float x = fminf(fmaxf(rgb[c], 0.0f), 1.0f);
                float sr = (x <= 0.0031308f)
                         ? 12.92f * x
                         : fmaf(1.055f, exp2f(log2f(x) * (1.0f/2.4f)), -0.055f);
                out[3*idx+c] = fmaf(grd_rgb[3*idx+c], a, sr * (1.0f - a));
            }
        }
    }
}

extern "C" void kernel_launch(void* const* d_in, const int* in_sizes, int n_in,
                              void* d_out, int out_size, void* d_ws, size_t ws_size,
                              hipStream_t stream) {
    const float* surf      = (const float*)d_in[0];
    const float* ray_o     = (const float*)d_in[1];
    const float* norm_raw  = (const float*)d_in[2];
    const float* albedo    = (const float*)d_in[3];
    const float* roughness = (const float*)d_in[4];
    const float* lvis      = (const float*)d_in[5];
    const float* xyz       = (const float*)d_in[6];
    const float* area      = (const float*)d_in[7];
    const float* probe     = (const float*)d_in[8];
    const float* grd_rgb   = (const float*)d_in[9];
    const float* grd_acc   = (const float*)d_in[10];
    const int*   inds      = (const int*)d_in[11];
    float* out = (float*)d_out;

    bg_kernel<<<PT_PTS/4/256, 256, 0, stream>>>((const float4*)grd_rgb,
        (const float4*)grd_acc, (float4*)out);
    render_kernel<<<P_PTS/4, 256, 0, stream>>>(surf, ray_o, norm_raw, albedo,
        roughness, lvis, xyz, area, probe, grd_rgb, grd_acc, inds, out);
}

// Round 6
// 26.780 us; speedup vs baseline: 1.8262x; 1.0348x over previous
//
#include <hip/hip_runtime.h>
#include <math.h>

#define NL     512      // EH*EW = 16*32
#define EH_C   16
#define EW_C   32
#define P_PTS  8192
#define PT_PTS 65536

typedef float f32x2 __attribute__((ext_vector_type(2)));

__device__ __forceinline__ float rcp_f(float x)  { return __builtin_amdgcn_rcpf(x); }
__device__ __forceinline__ float rsq_f(float x)  { return __builtin_amdgcn_rsqf(x); }
__device__ __forceinline__ float sqrt_f(float x) { return __builtin_amdgcn_sqrtf(x); }

__device__ __forceinline__ f32x2 rcp2(f32x2 x)  { return (f32x2){rcp_f(x.x),  rcp_f(x.y)}; }
__device__ __forceinline__ f32x2 rsq2(f32x2 x)  { return (f32x2){rsq_f(x.x),  rsq_f(x.y)}; }
__device__ __forceinline__ f32x2 sqrt2(f32x2 x) { return (f32x2){sqrt_f(x.x), sqrt_f(x.y)}; }
__device__ __forceinline__ f32x2 floor2(f32x2 x){ return (f32x2){floorf(x.x), floorf(x.y)}; }
__device__ __forceinline__ f32x2 abs2(f32x2 x)  { return (f32x2){fabsf(x.x),  fabsf(x.y)}; }
__device__ __forceinline__ f32x2 max2(f32x2 a, f32x2 b){ return (f32x2){fmaxf(a.x,b.x), fmaxf(a.y,b.y)}; }
__device__ __forceinline__ f32x2 min2(f32x2 a, f32x2 b){ return (f32x2){fminf(a.x,b.x), fminf(a.y,b.y)}; }
__device__ __forceinline__ f32x2 maxs(f32x2 a, float b){ return (f32x2){fmaxf(a.x,b), fmaxf(a.y,b)}; }

// out = grd_rgb * acc, fully vectorized: thread j handles 4 points (12 floats).
__global__ __launch_bounds__(256) void bg_kernel(const float4* __restrict__ rgbv,
                                                 const float4* __restrict__ accv,
                                                 float4* __restrict__ outv) {
    int j = blockIdx.x * 256 + threadIdx.x;   // 16384 threads
    float4 a  = accv[j];
    float4 r0 = rgbv[3*j+0], r1 = rgbv[3*j+1], r2 = rgbv[3*j+2];
    outv[3*j+0] = make_float4(r0.x*a.x, r0.y*a.x, r0.z*a.x, r0.w*a.y);
    outv[3*j+1] = make_float4(r1.x*a.y, r1.y*a.y, r1.z*a.z, r1.w*a.z);
    outv[3*j+2] = make_float4(r2.x*a.z, r2.y*a.w, r2.z*a.w, r2.w*a.w);
}

// one wave64 per point; lanes split the 512 lights, 2 lights/lane/iter (packed f32)
__global__ __launch_bounds__(256, 4) void render_kernel(
    const float* __restrict__ surf,      // P,3
    const float* __restrict__ ray_o,     // P,3
    const float* __restrict__ norm_raw,  // P,3
    const float* __restrict__ albedo,    // P,3
    const float* __restrict__ rough,     // P,1
    const float* __restrict__ lvis,      // P,512
    const float* __restrict__ xyz,       // 512,3
    const float* __restrict__ area,      // 512
    const float* __restrict__ probe,     // 512,3
    const float* __restrict__ grd_rgb,   // Pt,3
    const float* __restrict__ grd_acc,   // Pt
    const int*   __restrict__ inds,      // P (sorted)
    float* __restrict__ out)             // Pt,3
{
    __shared__ float4 sA[NL];   // xyz.xyz, w = area/(|xyz|+1e-8)
    __shared__ float4 sP[NL];   // probe rgb, pad

    for (int i = threadIdx.x; i < NL; i += 256) {
        float x = xyz[3*i+0], y = xyz[3*i+1], z = xyz[3*i+2];
        float aw = area[i] / (sqrtf(x*x + y*y + z*z) + 1e-8f);
        sA[i] = make_float4(x, y, z, aw);
        sP[i] = make_float4(probe[3*i+0], probe[3*i+1], probe[3*i+2], 0.0f);
    }
    __syncthreads();

    const int lane = threadIdx.x & 63;
    const int p    = blockIdx.x * 4 + (threadIdx.x >> 6);

    // ---- per-point precompute (redundant per lane, amortized over 8 lights) ----
    float sx = surf[3*p+0], sy = surf[3*p+1], sz = surf[3*p+2];
    float nx = norm_raw[3*p+0], ny = norm_raw[3*p+1], nz = norm_raw[3*p+2];
    { float inv = 1.0f / (sqrtf(nx*nx + ny*ny + nz*nz) + 1e-8f); nx*=inv; ny*=inv; nz*=inv; }
    float cx = ray_o[3*p+0]-sx, cy = ray_o[3*p+1]-sy, cz = ray_o[3*p+2]-sz;
    { float inv = 1.0f / (sqrtf(cx*cx + cy*cy + cz*cz) + 1e-8f); cx*=inv; cy*=inv; cz*=inv; }

    float cos_v  = nx*cx + ny*cy + nz*cz;
    float r      = rough[p];
    float alpha2 = (r*r)*(r*r);
    float cvsq   = fminf(fmaxf(cos_v*cos_v, 0.0f), 1.0f);
    float tvsq   = (cvsq > 1e-12f) ? fminf((1.0f - cvsq)/cvsq, 1e10f) : 0.0f;
    float gden   = 1.0f + sqrtf(1.0f + alpha2 * tvsq);
    // chi_g == (cos_v > 0) since l.h >= 0 always; |cos_v|<=1e-12 edge also folded here.
    float g2a    = (cos_v > 1e-12f) ? (2.0f / gden) * alpha2 * 0.3183098862f : 0.0f;
    float a2m1   = alpha2 - 1.0f;
    float acv4   = 4.0f * fabsf(cos_v);
    float ab0 = albedo[3*p+0] * 0.3183098862f;
    float ab1 = albedo[3*p+1] * 0.3183098862f;
    float ab2 = albedo[3*p+2] * 0.3183098862f;
    const float* lv = lvis + p*NL;

    f32x2 acc0 = (f32x2)(0.0f), acc1 = (f32x2)(0.0f), acc2 = (f32x2)(0.0f);

    #pragma unroll
    for (int it = 0; it < 4; ++it) {
        int l0 = lane + it*64;
        int l1 = l0 + 256;
        float lva = lv[l0], lvb = lv[l1];
        float4 A0 = sA[l0], A1 = sA[l1];
        f32x2 Ax = {A0.x, A1.x}, Ay = {A0.y, A1.y}, Az = {A0.z, A1.z}, Aw = {A0.w, A1.w};

        // surf2light (|d| ~ O(10): no zero guard needed)
        f32x2 dx = Ax - sx, dy = Ay - sy, dz = Az - sz;
        f32x2 inv = rsq2(dx*dx + dy*dy + dz*dz);
        f32x2 slx = dx*inv, sly = dy*inv, slz = dz*inv;

        // sh = lvis * (n . xyz) * (area/|xyz|)
        f32x2 sh = ((f32x2){lva, lvb}) * (Ax*nx + Ay*ny + Az*nz) * Aw;

        // ---- v = acos(zc)*K - 0.5  (K=16/pi folded into poly) ----
        f32x2 zc = min2(maxs(slz, -0.999999f), (f32x2)(0.999999f));
        f32x2 xa = abs2(zc);
        f32x2 pcl = ((xa*-0.0953875f + 0.378208f)*xa - 1.0802913f)*xa + 7.9996562f;
        f32x2 vpre = sqrt2(1.0f - xa) * pcl;              // acos(|zc|)*K
        f32x2 vv;
        vv.x = (zc.x < 0.0f) ? (15.5f - vpre.x) : (vpre.x - 0.5f);
        vv.y = (zc.y < 0.0f) ? (15.5f - vpre.y) : (vpre.y - 0.5f);

        // ---- u = atan2(sly,slx)*K + 15.5 ; K*pi/2 = 8, K*pi = 16 exact ----
        f32x2 axv = abs2(slx), ayv = abs2(sly);
        f32x2 mx = max2(axv, ayv), mn = min2(axv, ayv);
        f32x2 a  = mn * rcp2(maxs(mx, 1e-37f));
        f32x2 s  = a * a;
        f32x2 pu = (((s*0.106112f - 0.433578f)*s + 0.917450f)*s - 1.682201f)*s + 5.0922757f;
        f32x2 rk = a * pu;                                 // atan(a)*K
        rk.x = (ayv.x > axv.x) ? 8.0f  - rk.x : rk.x;
        rk.y = (ayv.y > axv.y) ? 8.0f  - rk.y : rk.y;
        rk.x = (slx.x < 0.0f)  ? 16.0f - rk.x : rk.x;
        rk.y = (slx.y < 0.0f)  ? 16.0f - rk.y : rk.y;
        f32x2 uu = { copysignf(rk.x, sly.x) + 15.5f,
                     copysignf(rk.y, sly.y) + 15.5f };

        // ---- bilinear weights (packed) ----
        f32x2 v0f = floor2(vv), u0f = floor2(uu);
        f32x2 fv = vv - v0f, fu = uu - u0f;
        f32x2 w11 = fu*fv, w10 = fv - w11, w01 = fu - w11;
        f32x2 w00 = (1.0f - fu) - w10;

        // ---- microfacet (packed): |h|^2=2+2hdot; ldh=(1+hdot)/|h|; cm=(ldn+cos_v)/|h| ----
        f32x2 hdot = slx*cx + sly*cy + slz*cz;
        f32x2 ih   = rsq2(maxs(hdot*2.0f + 2.0f, 1e-12f));
        f32x2 ldh  = (1.0f + hdot) * ih;
        f32x2 ldn  = slx*nx + sly*ny + slz*nz;
        f32x2 cm   = (ldn + cos_v) * ih;
        f32x2 om   = 1.0f - ldh;
        f32x2 om2  = om*om;
        f32x2 ff   = om2*om2*om*0.09f + 0.91f;
        f32x2 q    = cm*cm*a2m1 + 1.0f;                    // cm^4*(a2+tan^2m) collapsed
        f32x2 den  = abs2(ldn) * acv4;
        f32x2 micro = ff * g2a * rcp2(q*q*den);            // single rcp for D and 1/den
        micro.x = (cm.x > 1e-6f && den.x > 1e-12f) ? micro.x : 0.0f;
        micro.y = (cm.y > 1e-6f && den.y > 1e-12f) ? micro.y : 0.0f;

        // ---- probe gathers (scalar per light) ----
        int v0a = (int)v0f.x; v0a = v0a < 0 ? 0 : v0a;  int v1a = v0a+1 > 15 ? 15 : v0a+1;
        int u0a = ((int)u0f.x) & 31;                    int u1a = (u0a+1) & 31;
        int v0b = (int)v0f.y; v0b = v0b < 0 ? 0 : v0b;  int v1b = v0b+1 > 15 ? 15 : v0b+1;
        int u0b = ((int)u0f.y) & 31;                    int u1b = (u0b+1) & 31;
        int r0a = v0a<<5, r1a = v1a<<5, r0b = v0b<<5, r1b = v1b<<5;
        float4 t00a = sP[r0a+u0a], t01a = sP[r0a+u1a], t10a = sP[r1a+u0a], t11a = sP[r1a+u1a];
        float4 t00b = sP[r0b+u0b], t01b = sP[r0b+u1b], t10b = sP[r1b+u0b], t11b = sP[r1b+u1b];

        f32x2 li0 = { fmaf(t00a.x,w00.x, fmaf(t01a.x,w01.x, fmaf(t10a.x,w10.x, t11a.x*w11.x))),
                      fmaf(t00b.x,w00.y, fmaf(t01b.x,w01.y, fmaf(t10b.x,w10.y, t11b.x*w11.y))) };
        f32x2 li1 = { fmaf(t00a.y,w00.x, fmaf(t01a.y,w01.x, fmaf(t10a.y,w10.x, t11a.y*w11.x))),
                      fmaf(t00b.y,w00.y, fmaf(t01b.y,w01.y, fmaf(t10b.y,w10.y, t11b.y*w11.y))) };
        f32x2 li2 = { fmaf(t00a.z,w00.x, fmaf(t01a.z,w01.x, fmaf(t10a.z,w10.x, t11a.z*w11.x))),
                      fmaf(t00b.z,w00.y, fmaf(t01b.z,w01.y, fmaf(t10b.z,w10.y, t11b.z*w11.y))) };

        acc0 += (micro + ab0) * (sh * li0);
        acc1 += (micro + ab1) * (sh * li1);
        acc2 += (micro + ab2) * (sh * li2);
    }

    float c0 = acc0.x + acc0.y;
    float c1 = acc1.x + acc1.y;
    float c2 = acc2.x + acc2.y;

    // wave64 butterfly reduce
    for (int off = 32; off > 0; off >>= 1) {
        c0 += __shfl_xor(c0, off);
        c1 += __shfl_xor(c1, off);
        c2 += __shfl_xor(c2, off);
    }

    if (lane == 0) {
        int idx = inds[p];
        // numpy scatter-set: last write wins; inds sorted -> only last occurrence writes
        bool last = (p == P_PTS-1) || (inds[p+1] != idx);
        if (last) {
            float a = grd_acc[idx];
            float rgb[3] = {c0, c1, c2};
            #pragma unroll
            for (int c = 0; c < 3; ++c) {
                float x = fminf(fmaxf(rgb[c], 0.0f), 1.0f);
                float sr = (x <= 0.0031308f)
                         ? 12.92f * x
                         : fmaf(1.055f, exp2f(log2f(x) * (1.0f/2.4f)), -0.055f);
                out[3*idx+c] = fmaf(grd_rgb[3*idx+c], a, sr * (1.0f - a));
            }
        }
    }
}

extern "C" void kernel_launch(void* const* d_in, const int* in_sizes, int n_in,
                              void* d_out, int out_size, void* d_ws, size_t ws_size,
                              hipStream_t stream) {
    const float* surf      = (const float*)d_in[0];
    const float* ray_o     = (const float*)d_in[1];
    const float* norm_raw  = (const float*)d_in[2];
    const float* albedo    = (const float*)d_in[3];
    const float* roughness = (const float*)d_in[4];
    const float* lvis      = (const float*)d_in[5];
    const float* xyz       = (const float*)d_in[6];
    const float* area      = (const float*)d_in[7];
    const float* probe     = (const float*)d_in[8];
    const float* grd_rgb   = (const float*)d_in[9];
    const float* grd_acc   = (const float*)d_in[10];
    const int*   inds      = (const int*)d_in[11];
    float* out = (float*)d_out;

    bg_kernel<<<PT_PTS/4/256, 256, 0, stream>>>((const float4*)grd_rgb,
        (const float4*)grd_acc, (float4*)out);
    render_kernel<<<P_PTS/4, 256, 0, stream>>>(surf, ray_o, norm_raw, albedo,
        roughness, lvis, xyz, area, probe, grd_rgb, grd_acc, inds, out);
}

// Round 7
// 26.761 us; speedup vs baseline: 1.8275x; 1.0007x over previous
//
#include <hip/hip_runtime.h>
#include <math.h>

#define NL     512      // EH*EW = 16*32
#define EH_C   16
#define EW_C   32
#define P_PTS  8192
#define PT_PTS 65536
#define PROW   33       // probe tile row stride (col 32 = col 0 dup)
#define PTILE  (17*33)  // row 16 = row 15 dup

typedef float f32x2 __attribute__((ext_vector_type(2)));

__device__ __forceinline__ float rcp_f(float x)  { return __builtin_amdgcn_rcpf(x); }
__device__ __forceinline__ float rsq_f(float x)  { return __builtin_amdgcn_rsqf(x); }
__device__ __forceinline__ float sqrt_f(float x) { return __builtin_amdgcn_sqrtf(x); }

__device__ __forceinline__ f32x2 rcp2(f32x2 x)  { return (f32x2){rcp_f(x.x),  rcp_f(x.y)}; }
__device__ __forceinline__ f32x2 rsq2(f32x2 x)  { return (f32x2){rsq_f(x.x),  rsq_f(x.y)}; }
__device__ __forceinline__ f32x2 sqrt2(f32x2 x) { return (f32x2){sqrt_f(x.x), sqrt_f(x.y)}; }
__device__ __forceinline__ f32x2 floor2(f32x2 x){ return (f32x2){floorf(x.x), floorf(x.y)}; }
__device__ __forceinline__ f32x2 abs2(f32x2 x)  { return (f32x2){fabsf(x.x),  fabsf(x.y)}; }
__device__ __forceinline__ f32x2 max2(f32x2 a, f32x2 b){ return (f32x2){fmaxf(a.x,b.x), fmaxf(a.y,b.y)}; }
__device__ __forceinline__ f32x2 min2(f32x2 a, f32x2 b){ return (f32x2){fminf(a.x,b.x), fminf(a.y,b.y)}; }
__device__ __forceinline__ f32x2 maxs(f32x2 a, float b){ return (f32x2){fmaxf(a.x,b), fmaxf(a.y,b)}; }

// out = grd_rgb * acc, fully vectorized: thread j handles 4 points (12 floats).
__global__ __launch_bounds__(256) void bg_kernel(const float4* __restrict__ rgbv,
                                                 const float4* __restrict__ accv,
                                                 float4* __restrict__ outv) {
    int j = blockIdx.x * 256 + threadIdx.x;   // 16384 threads
    float4 a  = accv[j];
    float4 r0 = rgbv[3*j+0], r1 = rgbv[3*j+1], r2 = rgbv[3*j+2];
    outv[3*j+0] = make_float4(r0.x*a.x, r0.y*a.x, r0.z*a.x, r0.w*a.y);
    outv[3*j+1] = make_float4(r1.x*a.y, r1.y*a.y, r1.z*a.z, r1.w*a.z);
    outv[3*j+2] = make_float4(r2.x*a.z, r2.y*a.w, r2.z*a.w, r2.w*a.w);
}

// one wave64 per point; lanes split the 512 lights, 2 lights/lane/iter (packed f32)
__global__ __launch_bounds__(256, 4) void render_kernel(
    const float* __restrict__ surf,      // P,3
    const float* __restrict__ ray_o,     // P,3
    const float* __restrict__ norm_raw,  // P,3
    const float* __restrict__ albedo,    // P,3
    const float* __restrict__ rough,     // P,1
    const float* __restrict__ lvis,      // P,512
    const float* __restrict__ xyz,       // 512,3
    const float* __restrict__ area,      // 512
    const float* __restrict__ probe,     // 512,3
    const float* __restrict__ grd_rgb,   // Pt,3
    const float* __restrict__ grd_acc,   // Pt
    const int*   __restrict__ inds,      // P (sorted)
    float* __restrict__ out)             // Pt,3
{
    __shared__ float4 sA[NL];     // xyz.xyz, w = area/(|xyz|+1e-8)
    __shared__ float4 sP2[PTILE]; // probe rgb, border-duplicated: [17][33], col32=col0, row16=row15

    for (int i = threadIdx.x; i < NL; i += 256) {
        float x = xyz[3*i+0], y = xyz[3*i+1], z = xyz[3*i+2];
        float aw = area[i] / (sqrtf(x*x + y*y + z*z) + 1e-8f);
        sA[i] = make_float4(x, y, z, aw);
    }
    for (int i = threadIdx.x; i < PTILE; i += 256) {
        int vr = i / PROW;          // const divisor -> magic mul
        int ur = i - vr * PROW;
        int sv = vr > 15 ? 15 : vr;
        int su = ur & 31;           // 32 -> 0 (wrap dup)
        int t  = sv * EW_C + su;
        sP2[i] = make_float4(probe[3*t+0], probe[3*t+1], probe[3*t+2], 0.0f);
    }
    __syncthreads();

    const int lane = threadIdx.x & 63;
    const int p    = blockIdx.x * 4 + (threadIdx.x >> 6);

    // ---- per-point precompute (redundant per lane, amortized over 8 lights) ----
    float sx = surf[3*p+0], sy = surf[3*p+1], sz = surf[3*p+2];
    float nx = norm_raw[3*p+0], ny = norm_raw[3*p+1], nz = norm_raw[3*p+2];
    { float inv = 1.0f / (sqrtf(nx*nx + ny*ny + nz*nz) + 1e-8f); nx*=inv; ny*=inv; nz*=inv; }
    float cx = ray_o[3*p+0]-sx, cy = ray_o[3*p+1]-sy, cz = ray_o[3*p+2]-sz;
    { float inv = 1.0f / (sqrtf(cx*cx + cy*cy + cz*cz) + 1e-8f); cx*=inv; cy*=inv; cz*=inv; }

    float cos_v  = nx*cx + ny*cy + nz*cz;
    float r      = rough[p];
    float alpha2 = (r*r)*(r*r);
    float cvsq   = fminf(fmaxf(cos_v*cos_v, 0.0f), 1.0f);
    float tvsq   = (cvsq > 1e-12f) ? fminf((1.0f - cvsq)/cvsq, 1e10f) : 0.0f;
    float gden   = 1.0f + sqrtf(1.0f + alpha2 * tvsq);
    // chi_g == (cos_v > 0) since l.h >= 0 always; |cos_v|<=1e-12 edge also folded here.
    float g2a    = (cos_v > 1e-12f) ? (2.0f / gden) * alpha2 * 0.3183098862f : 0.0f;
    float a2m1   = alpha2 - 1.0f;
    float acv4   = 4.0f * fabsf(cos_v);
    float ab0 = albedo[3*p+0] * 0.3183098862f;
    float ab1 = albedo[3*p+1] * 0.3183098862f;
    float ab2 = albedo[3*p+2] * 0.3183098862f;
    const float* lv = lvis + p*NL;

    f32x2 acc0 = (f32x2)(0.0f), acc1 = (f32x2)(0.0f), acc2 = (f32x2)(0.0f);

    #pragma unroll
    for (int it = 0; it < 4; ++it) {
        int l0 = lane + it*64;
        int l1 = l0 + 256;
        float lva = lv[l0], lvb = lv[l1];
        float4 A0 = sA[l0], A1 = sA[l1];
        f32x2 Ax = {A0.x, A1.x}, Ay = {A0.y, A1.y}, Az = {A0.z, A1.z}, Aw = {A0.w, A1.w};

        // surf2light (|d| ~ O(10): no zero guard needed)
        f32x2 dx = Ax - sx, dy = Ay - sy, dz = Az - sz;
        f32x2 inv = rsq2(dx*dx + dy*dy + dz*dz);
        f32x2 slx = dx*inv, sly = dy*inv, slz = dz*inv;

        // sh = lvis * (n . xyz) * (area/|xyz|)
        f32x2 sh = ((f32x2){lva, lvb}) * (Ax*nx + Ay*ny + Az*nz) * Aw;

        // ---- v = acos(zc)*K - 0.5  (K=16/pi folded into poly) ----
        f32x2 zc = min2(maxs(slz, -0.999999f), (f32x2)(0.999999f));
        f32x2 xa = abs2(zc);
        f32x2 pcl = ((xa*-0.0953875f + 0.378208f)*xa - 1.0802913f)*xa + 7.9996562f;
        f32x2 vpre = sqrt2(1.0f - xa) * pcl;              // acos(|zc|)*K
        f32x2 vv;
        vv.x = (zc.x < 0.0f) ? (15.5f - vpre.x) : (vpre.x - 0.5f);
        vv.y = (zc.y < 0.0f) ? (15.5f - vpre.y) : (vpre.y - 0.5f);

        // ---- u = atan2(sly,slx)*K + 15.5 ; K*pi/2 = 8, K*pi = 16 exact ----
        f32x2 axv = abs2(slx), ayv = abs2(sly);
        f32x2 mx = max2(axv, ayv), mn = min2(axv, ayv);
        f32x2 a  = mn * rcp2(maxs(mx, 1e-37f));
        f32x2 s  = a * a;
        f32x2 pu = (((s*0.106112f - 0.433578f)*s + 0.917450f)*s - 1.682201f)*s + 5.0922757f;
        f32x2 rk = a * pu;                                 // atan(a)*K
        rk.x = (ayv.x > axv.x) ? 8.0f  - rk.x : rk.x;
        rk.y = (ayv.y > axv.y) ? 8.0f  - rk.y : rk.y;
        rk.x = (slx.x < 0.0f)  ? 16.0f - rk.x : rk.x;
        rk.y = (slx.y < 0.0f)  ? 16.0f - rk.y : rk.y;
        f32x2 uu = { copysignf(rk.x, sly.x) + 15.5f,
                     copysignf(rk.y, sly.y) + 15.5f };

        // ---- bilinear weights (packed) ----
        f32x2 v0f = floor2(vv), u0f = floor2(uu);
        f32x2 fv = vv - v0f, fu = uu - u0f;
        f32x2 w11 = fu*fv, w10 = fv - w11, w01 = fu - w11;
        f32x2 w00 = (1.0f - fu) - w10;

        // ---- microfacet (packed): |h|^2=2+2hdot; ldh=(1+hdot)/|h|; cm=(ldn+cos_v)/|h| ----
        f32x2 hdot = slx*cx + sly*cy + slz*cz;
        f32x2 ih   = rsq2(maxs(hdot*2.0f + 2.0f, 1e-12f));
        f32x2 ldh  = (1.0f + hdot) * ih;
        f32x2 ldn  = slx*nx + sly*ny + slz*nz;
        f32x2 cm   = (ldn + cos_v) * ih;
        f32x2 om   = 1.0f - ldh;
        f32x2 om2  = om*om;
        f32x2 ff   = om2*om2*om*0.09f + 0.91f;
        f32x2 q    = cm*cm*a2m1 + 1.0f;                    // cm^4*(a2+tan^2m) collapsed
        f32x2 den  = abs2(ldn) * acv4;
        f32x2 micro = ff * g2a * rcp2(q*q*den);            // single rcp for D and 1/den
        micro.x = (cm.x > 1e-6f && den.x > 1e-12f) ? micro.x : 0.0f;
        micro.y = (cm.y > 1e-6f && den.y > 1e-12f) ? micro.y : 0.0f;

        // ---- probe gathers: ONE address per light; +1/+33/+34 are imm offsets.
        // Border-duplicated tile makes u1=u0+1, v1=v0+1 unconditionally valid.
        int v0a = (int)v0f.x; v0a = v0a < 0 ? 0 : v0a;     // v <= 15.5 -> floor <= 15
        int u0a = ((int)u0f.x) & 31;                       // floor(u) in [-1,31]; -1 -> 31 ok
        int v0b = (int)v0f.y; v0b = v0b < 0 ? 0 : v0b;
        int u0b = ((int)u0f.y) & 31;
        const float4* pa = &sP2[v0a*PROW + u0a];
        const float4* pb = &sP2[v0b*PROW + u0b];
        float4 t00a = pa[0], t01a = pa[1], t10a = pa[PROW], t11a = pa[PROW+1];
        float4 t00b = pb[0], t01b = pb[1], t10b = pb[PROW], t11b = pb[PROW+1];

        f32x2 li0 = { fmaf(t00a.x,w00.x, fmaf(t01a.x,w01.x, fmaf(t10a.x,w10.x, t11a.x*w11.x))),
                      fmaf(t00b.x,w00.y, fmaf(t01b.x,w01.y, fmaf(t10b.x,w10.y, t11b.x*w11.y))) };
        f32x2 li1 = { fmaf(t00a.y,w00.x, fmaf(t01a.y,w01.x, fmaf(t10a.y,w10.x, t11a.y*w11.x))),
                      fmaf(t00b.y,w00.y, fmaf(t01b.y,w01.y, fmaf(t10b.y,w10.y, t11b.y*w11.y))) };
        f32x2 li2 = { fmaf(t00a.z,w00.x, fmaf(t01a.z,w01.x, fmaf(t10a.z,w10.x, t11a.z*w11.x))),
                      fmaf(t00b.z,w00.y, fmaf(t01b.z,w01.y, fmaf(t10b.z,w10.y, t11b.z*w11.y))) };

        acc0 += (micro + ab0) * (sh * li0);
        acc1 += (micro + ab1) * (sh * li1);
        acc2 += (micro + ab2) * (sh * li2);
    }

    float c0 = acc0.x + acc0.y;
    float c1 = acc1.x + acc1.y;
    float c2 = acc2.x + acc2.y;

    // wave64 butterfly reduce
    for (int off = 32; off > 0; off >>= 1) {
        c0 += __shfl_xor(c0, off);
        c1 += __shfl_xor(c1, off);
        c2 += __shfl_xor(c2, off);
    }

    if (lane == 0) {
        int idx = inds[p];
        // numpy scatter-set: last write wins; inds sorted -> only last occurrence writes
        bool last = (p == P_PTS-1) || (inds[p+1] != idx);
        if (last) {
            float a = grd_acc[idx];
            float rgb[3] = {c0, c1, c2};
            #pragma unroll
            for (int c = 0; c < 3; ++c) {
                float x = fminf(fmaxf(rgb[c], 0.0f), 1.0f);
                float sr = (x <= 0.0031308f)
                         ? 12.92f * x
                         : fmaf(1.055f, exp2f(log2f(x) * (1.0f/2.4f)), -0.055f);
                out[3*idx+c] = fmaf(grd_rgb[3*idx+c], a, sr * (1.0f - a));
            }
        }
    }
}

extern "C" void kernel_launch(void* const* d_in, const int* in_sizes, int n_in,
                              void* d_out, int out_size, void* d_ws, size_t ws_size,
                              hipStream_t stream) {
    const float* surf      = (const float*)d_in[0];
    const float* ray_o     = (const float*)d_in[1];
    const float* norm_raw  = (const float*)d_in[2];
    const float* albedo    = (const float*)d_in[3];
    const float* roughness = (const float*)d_in[4];
    const float* lvis      = (const float*)d_in[5];
    const float* xyz       = (const float*)d_in[6];
    const float* area      = (const float*)d_in[7];
    const float* probe     = (const float*)d_in[8];
    const float* grd_rgb   = (const float*)d_in[9];
    const float* grd_acc   = (const float*)d_in[10];
    const int*   inds      = (const int*)d_in[11];
    float* out = (float*)d_out;

    bg_kernel<<<PT_PTS/4/256, 256, 0, stream>>>((const float4*)grd_rgb,
        (const float4*)grd_acc, (float4*)out);
    render_kernel<<<P_PTS/4, 256, 0, stream>>>(surf, ray_o, norm_raw, albedo,
        roughness, lvis, xyz, area, probe, grd_rgb, grd_acc, inds, out);
}